// Round 4
// baseline (235.059 us; speedup 1.0000x reference)
//
#include <hip/hip_runtime.h>

// Problem constants (fixed by setup_inputs)
#define NT    8           // timesteps
#define NB    16          // batch
#define FS    262144      // C*H*W (= 2^18)
#define TPB   256         // threads per block
#define BPB   32          // blocks per batch
#define GRID  (NB*BPB)    // 512 blocks = 2/CU
#define CHK   8           // float4 chunks/thread -> 32 elems/thread
#define ELB   (TPB*CHK*4) // 8192 elems per block
#define SPIN_CAP (1L<<26)

// ws layout (zeroed every launch):
//   bsum double[NT][NB][BPB] @ 0      (32768 B) per-block |m| sums, stored -bs
//                                      (nonzero BIT pattern = ready flag)
//   dbc  double[NT][NB]      @ 32768  (1024 B)  denom broadcast (>=1e-6, so
//                                      value itself is the ready flag)
//   cnt  int[NB][NT][BPB]    @ 33792  (16384 B) spike counts, stored count+1
//   cbc  int[NB][NT]         @ 50176  (512 B)   count totals bcast, stored +1
#define WS_NEED 50688

__global__ __launch_bounds__(TPB, 2)
void bispike_kernel(const float* __restrict__ x,
                    const float* __restrict__ decay_p,
                    const float* __restrict__ vth_p,
                    const float* __restrict__ W1,
                    const float* __restrict__ b1,
                    const float* __restrict__ W2,
                    const float* __restrict__ b2,
                    const float* __restrict__ att_w,
                    float* __restrict__ out,
                    double* __restrict__ bsum,
                    double* __restrict__ dbc,
                    int* __restrict__ cnt,
                    int* __restrict__ cbc)
{
    const int tid  = threadIdx.x;
    const int lane = tid & 63;
    const int wid  = tid >> 6;
    // XCD-localized batches: batch b's 32 blocks all on XCD b%8;
    // leader (bg==0) blocks are wgs 0..15 -> 16 distinct CUs.
    const int b    = blockIdx.x % NB;
    const int bg   = blockIdx.x / NB;
    const bool leader = (bg == 0);

    // fp64 reference process: sigmoid, threshold, all state in double
    const double dec  = 1.0 / (1.0 + exp(-(double)decay_p[0]));
    const double vth  = (double)vth_p[0];
    const double csub = dec * vth;            // loop-invariant spike correction

    double   u[CHK * 4];           // unnormalized membrane m_t (fp64)
    float4   xv[CHK];              // prefetched x (fp32 in memory)
    unsigned sm[NT];               // spike bits (32 used)

    {   // t=0: m_0 = x_0 (carry is zero)
        const float* p = x + (size_t)b * FS + (size_t)bg * ELB + tid * 4;
        #pragma unroll
        for (int k = 0; k < CHK; ++k) xv[k] = *(const float4*)(p + k * (TPB * 4));
    }
    double lsum;
    {
        double n0 = 0.0, n1 = 0.0, n2 = 0.0, n3 = 0.0;
        #pragma unroll
        for (int k = 0; k < CHK; ++k) {
            u[k*4+0] = (double)xv[k].x; n0 += fabs(u[k*4+0]);
            u[k*4+1] = (double)xv[k].y; n1 += fabs(u[k*4+1]);
            u[k*4+2] = (double)xv[k].z; n2 += fabs(u[k*4+2]);
            u[k*4+3] = (double)xv[k].w; n3 += fabs(u[k*4+3]);
        }
        lsum = (n0 + n1) + (n2 + n3);
    }

    __shared__ double dred[4];
    __shared__ double denom_s;

    #pragma unroll 1
    for (int t = 0; t < NT; ++t) {
        // prefetch x[t+1]; overlaps the whole exchange below
        if (t < NT - 1) {
            const float* p = x + ((size_t)(t + 1) * NB + b) * FS
                               + (size_t)bg * ELB + tid * 4;
            #pragma unroll
            for (int k = 0; k < CHK; ++k) xv[k] = *(const float4*)(p + k * (TPB * 4));
        }

        // ---- wave partial of sum |m_t| ----
        double ls = lsum;
        #pragma unroll
        for (int off = 32; off > 0; off >>= 1)
            ls += __shfl_down(ls, off, 64);
        if (lane == 0) dred[wid] = ls;
        __syncthreads();           // waves 1-3 sleep until denom is ready

        if (tid < 64) {
            const double bs = (dred[0] + dred[1]) + (dred[2] + dred[3]);
            double* slot = bsum + (size_t)(t * NB + b) * BPB;
            if (!leader) {
                // follower: publish partial, then 1-lane throttled poll of denom
                if (lane == 0) {
                    __hip_atomic_store(slot + bg, -bs, __ATOMIC_RELAXED,
                                       __HIP_MEMORY_SCOPE_AGENT);
                    double dv; long it = 0;
                    for (;;) {
                        dv = __hip_atomic_load(&dbc[t * NB + b], __ATOMIC_RELAXED,
                                               __HIP_MEMORY_SCOPE_AGENT);
                        if (__double_as_longlong(dv) != 0) break;
                        if (++it > SPIN_CAP) break;
                        __builtin_amdgcn_s_sleep(8);   // ~512 cyc backoff
                    }
                    denom_s = dv;
                }
            } else {
                // leader: gather 31 partials (own local), reduce, broadcast
                const bool act = (lane >= 1 && lane < 32);
                double v = 0.0; long it = 0;
                for (;;) {
                    if (act)
                        v = __hip_atomic_load(slot + lane, __ATOMIC_RELAXED,
                                              __HIP_MEMORY_SCOPE_AGENT);
                    if (__all(!act || __double_as_longlong(v) != 0)) break;
                    if (++it > SPIN_CAP) break;
                    __builtin_amdgcn_s_sleep(2);       // ~128 cyc cadence
                }
                // slot i sits at lane i (lane0 = own) -> same reduce tree as R3
                double tot = (lane == 0) ? bs : ((lane < 32) ? -v : 0.0);
                #pragma unroll
                for (int off = 32; off > 0; off >>= 1)
                    tot += __shfl_down(tot, off, 64);
                if (lane == 0) {
                    const double dn = tot / (double)FS + 1e-6;  // exact /2^18
                    __hip_atomic_store(&dbc[t * NB + b], dn, __ATOMIC_RELAXED,
                                       __HIP_MEMORY_SCOPE_AGENT);
                    denom_s = dn;
                }
            }
        }
        __syncthreads();
        const double denom = denom_s;

        // fused threshold + advance:
        //   s_t  = (u >= vth*D_t)            (== m/D >= vth up to ~1e-15)
        //   u'   = (dec/D_t)*u + x' - s_t*(dec*vth)
        const double thr = vth * denom;
        const double a   = dec * (1.0 / denom);
        unsigned smt = 0;
        if (t < NT - 1) {
            double n0 = 0.0, n1 = 0.0, n2 = 0.0, n3 = 0.0;
            #pragma unroll
            for (int k = 0; k < CHK; ++k) {
                const double xn0 = (double)xv[k].x, xn1 = (double)xv[k].y,
                             xn2 = (double)xv[k].z, xn3 = (double)xv[k].w;
                double un;
                bool s0 = (u[k*4+0] >= thr); if (s0) smt |= 1u << (k*4+0);
                un = fma(a, u[k*4+0], xn0); if (s0) un -= csub;
                u[k*4+0] = un; n0 += fabs(un);
                bool s1 = (u[k*4+1] >= thr); if (s1) smt |= 1u << (k*4+1);
                un = fma(a, u[k*4+1], xn1); if (s1) un -= csub;
                u[k*4+1] = un; n1 += fabs(un);
                bool s2 = (u[k*4+2] >= thr); if (s2) smt |= 1u << (k*4+2);
                un = fma(a, u[k*4+2], xn2); if (s2) un -= csub;
                u[k*4+2] = un; n2 += fabs(un);
                bool s3 = (u[k*4+3] >= thr); if (s3) smt |= 1u << (k*4+3);
                un = fma(a, u[k*4+3], xn3); if (s3) un -= csub;
                u[k*4+3] = un; n3 += fabs(un);
            }
            lsum = (n0 + n1) + (n2 + n3);
        } else {
            #pragma unroll
            for (int j = 0; j < CHK * 4; ++j)
                if (u[j] >= thr) smt |= 1u << j;
        }
        sm[t] = smt;
    }

    // ---- spike counts per (t,b): exact integers, leader-tree exchange ----
    __shared__ int ired[NT][4];
    #pragma unroll
    for (int t = 0; t < NT; ++t) {
        int c = __popc(sm[t]);
        #pragma unroll
        for (int off = 32; off > 0; off >>= 1)
            c += __shfl_down(c, off, 64);
        if (lane == 0) ired[t][wid] = c;
    }
    __syncthreads();

    __shared__ double summ_s[NT];
    __shared__ int totc_s[NT];

    if (tid < 64) {
        int* cb = cnt + b * (NT * BPB);
        if (!leader) {
            if (lane < NT) {
                int tot = (ired[lane][0] + ired[lane][1])
                        + (ired[lane][2] + ired[lane][3]);
                __hip_atomic_store(cb + lane * BPB + bg, tot + 1,
                                   __ATOMIC_RELAXED, __HIP_MEMORY_SCOPE_AGENT);
            }
            const bool act = (lane < NT);
            int cv = 0; long it = 0;
            for (;;) {
                if (act)
                    cv = __hip_atomic_load(&cbc[b * NT + lane], __ATOMIC_RELAXED,
                                           __HIP_MEMORY_SCOPE_AGENT);
                if (__all(!act || cv != 0)) break;
                if (++it > SPIN_CAP) break;
                __builtin_amdgcn_s_sleep(8);
            }
            if (act) totc_s[lane] = cv - 1;
        } else {
            const bool act = (lane >= 1 && lane < 32);
            int vt[NT]; long it = 0;
            for (;;) {
                bool ok = true;
                #pragma unroll
                for (int t = 0; t < NT; ++t) {
                    if (act) {
                        vt[t] = __hip_atomic_load(cb + t * BPB + lane,
                                                  __ATOMIC_RELAXED,
                                                  __HIP_MEMORY_SCOPE_AGENT);
                        ok = ok && (vt[t] > 0);
                    }
                }
                if (__all(ok)) break;
                if (++it > SPIN_CAP) break;
                __builtin_amdgcn_s_sleep(2);
            }
            #pragma unroll
            for (int t = 0; t < NT; ++t) {
                int s;
                if (lane == 0)      s = (ired[t][0] + ired[t][1])
                                      + (ired[t][2] + ired[t][3]);
                else if (act)       s = vt[t] - 1;
                else                s = 0;
                #pragma unroll
                for (int off = 32; off > 0; off >>= 1)
                    s += __shfl_down(s, off, 64);
                if (lane == 0) {
                    totc_s[t] = s;
                    __hip_atomic_store(&cbc[b * NT + t], s + 1,
                                       __ATOMIC_RELAXED, __HIP_MEMORY_SCOPE_AGENT);
                }
            }
        }
    }
    __syncthreads();
    if (tid < NT)
        summ_s[tid] = (double)totc_s[tid] / (double)FS;    // exact
    __syncthreads();

    // ---- tiny MLP attention in fp64, redundantly per block ----
    __shared__ double h_s[4 * 64];
    __shared__ double wmat_s[NT];
    {
        int nh = tid >> 6, hd = tid & 63;
        double acc = 0.0;
        #pragma unroll
        for (int t = 0; t < NT; ++t)
            acc += summ_s[t] * (double)W1[nh * 512 + hd * 8 + t];
        acc += (double)b1[nh * 64 + hd];
        h_s[tid] = fmax(acc, 0.0);
    }
    __syncthreads();
    if (tid < NT) {
        double w = 0.0;
        for (int nh = 0; nh < 4; ++nh) {
            double macc = 0.0;
            for (int hd = 0; hd < 64; ++hd)
                macc += h_s[nh * 64 + hd] * (double)W2[nh * 512 + tid * 64 + hd];
            macc += (double)b2[nh * 8 + tid];
            w += macc * (double)att_w[nh];
        }
        wmat_s[tid] = w;
    }
    __syncthreads();

    // softmax over t in fp64 (per-thread copy)
    double awr[NT];
    {
        double mx = wmat_s[0];
        #pragma unroll
        for (int t = 1; t < NT; ++t) mx = fmax(mx, wmat_s[t]);
        double ss = 0.0;
        #pragma unroll
        for (int t = 0; t < NT; ++t) { awr[t] = exp(wmat_s[t] - mx); ss += awr[t]; }
        #pragma unroll
        for (int t = 0; t < NT; ++t) awr[t] = awr[t] / ss;
    }

    // ---- out[b,f] = sum_t spike_bit * aw[t,b] (fp64 acc, fp32 store) ----
    float* po = out + (size_t)b * FS + (size_t)bg * ELB + tid * 4;
    #pragma unroll
    for (int k = 0; k < CHK; ++k) {
        double o[4] = {0.0, 0.0, 0.0, 0.0};
        #pragma unroll
        for (int t = 0; t < NT; ++t) {
            const unsigned smt = sm[t];
            o[0] += ((smt >> (k * 4 + 0)) & 1) ? awr[t] : 0.0;
            o[1] += ((smt >> (k * 4 + 1)) & 1) ? awr[t] : 0.0;
            o[2] += ((smt >> (k * 4 + 2)) & 1) ? awr[t] : 0.0;
            o[3] += ((smt >> (k * 4 + 3)) & 1) ? awr[t] : 0.0;
        }
        *(float4*)(po + k * (TPB * 4)) =
            make_float4((float)o[0], (float)o[1], (float)o[2], (float)o[3]);
    }
}

__global__ void diag_kernel(float* out, int code) {
    out[0] = 100000.0f + (float)code;
}

extern "C" void kernel_launch(void* const* d_in, const int* in_sizes, int n_in,
                              void* d_out, int out_size, void* d_ws, size_t ws_size,
                              hipStream_t stream) {
    const float* x     = (const float*)d_in[0];
    const float* decay = (const float*)d_in[1];
    const float* vth   = (const float*)d_in[2];
    const float* W1    = (const float*)d_in[3];
    const float* b1    = (const float*)d_in[4];
    const float* W2    = (const float*)d_in[5];
    const float* b2    = (const float*)d_in[6];
    const float* att   = (const float*)d_in[7];
    float* out = (float*)d_out;

    if (ws_size < WS_NEED) {
        diag_kernel<<<1, 1, 0, stream>>>(out, 999);
        return;
    }

    double* bsum = (double*)d_ws;
    double* dbc  = (double*)((char*)d_ws + 32768);
    int*    cnt  = (int*)((char*)d_ws + 33792);
    int*    cbc  = (int*)((char*)d_ws + 50176);

    // control/accumulator region zeroed every launch (ws re-poisoned 0xAA)
    hipMemsetAsync(d_ws, 0, WS_NEED, stream);

    hipGetLastError();  // clear stale error
    bispike_kernel<<<dim3(GRID), dim3(TPB), 0, stream>>>(
        x, decay, vth, W1, b1, W2, b2, att, out, bsum, dbc, cnt, cbc);
    hipError_t err = hipGetLastError();
    if (err != hipSuccess) {
        diag_kernel<<<1, 1, 0, stream>>>(out, (int)err);
    }
}

// Round 5
// 233.034 us; speedup vs baseline: 1.0087x; 1.0087x over previous
//
#include <hip/hip_runtime.h>

// Problem constants (fixed by setup_inputs)
#define NT    8           // timesteps
#define NB    16          // batch
#define FS    262144      // C*H*W (= 2^18)
#define TPB   256         // threads per block
#define BPB   64          // blocks per batch (leader gather = exactly one wave)
#define GRID  (NB*BPB)    // 1024 blocks = 4/CU
#define CHK   4           // float4 chunks/thread -> 16 elems/thread
#define ELB   (TPB*CHK*4) // 4096 elems per block
#define SPIN_CAP (1L<<26)

// ws layout (zeroed every launch):
//   bsum double[NT][NB][BPB] @ 0      (65536 B) per-block |m| sums, stored -bs
//            (nonzero bits = ready; later REUSED for counts stored +(c+1) > 0,
//             distinguishable from stale -bs <= -0.0)
//   dbc  double[NT][NB]      @ 65536  (1024 B)  denom broadcast (> 0 = ready;
//            later REUSED for count totals stored -(tot+1) < 0)
#define WS_NEED 66560

__global__ __launch_bounds__(TPB, 4)
void bispike_kernel(const float* __restrict__ x,
                    const float* __restrict__ decay_p,
                    const float* __restrict__ vth_p,
                    const float* __restrict__ W1,
                    const float* __restrict__ b1,
                    const float* __restrict__ W2,
                    const float* __restrict__ b2,
                    const float* __restrict__ att_w,
                    float* __restrict__ out,
                    double* __restrict__ bsum,
                    double* __restrict__ dbc)
{
    const int tid  = threadIdx.x;
    const int lane = tid & 63;
    const int wid  = tid >> 6;
    // XCD-localized: batch b's 64 blocks on XCD b%8 (2 batches/XCD, 4 blocks/CU,
    // each CU hosts 2 blocks of each of 2 batches -> 4 interleaved phases).
    const int b    = blockIdx.x & 15;
    const int bg   = blockIdx.x >> 4;
    const bool leader = (bg == 0);

    // fp64 reference process: sigmoid, threshold, all state in double
    const double dec  = 1.0 / (1.0 + exp(-(double)decay_p[0]));
    const double vth  = (double)vth_p[0];
    const double csub = dec * vth;            // loop-invariant spike correction

    double   u[CHK * 4];           // unnormalized membrane m_t (fp64)
    float4   xv[CHK];              // prefetched x (fp32 in memory)
    unsigned sm[NT];               // spike bits (16 used)

    {   // t=0: m_0 = x_0 (carry is zero); loads fully consumed before exchange
        const float* p = x + (size_t)b * FS + (size_t)bg * ELB + tid * 4;
        #pragma unroll
        for (int k = 0; k < CHK; ++k) xv[k] = *(const float4*)(p + k * (TPB * 4));
    }
    double lsum;
    {
        double n0 = 0.0, n1 = 0.0, n2 = 0.0, n3 = 0.0;
        #pragma unroll
        for (int k = 0; k < CHK; ++k) {
            u[k*4+0] = (double)xv[k].x; n0 += fabs(u[k*4+0]);
            u[k*4+1] = (double)xv[k].y; n1 += fabs(u[k*4+1]);
            u[k*4+2] = (double)xv[k].z; n2 += fabs(u[k*4+2]);
            u[k*4+3] = (double)xv[k].w; n3 += fabs(u[k*4+3]);
        }
        lsum = (n0 + n1) + (n2 + n3);
    }

    __shared__ double dred[4];
    __shared__ double denom_s;

    #pragma unroll 1
    for (int t = 0; t < NT; ++t) {
        // early prefetch for NON-exchange waves only: keeps wave0's VMEM FIFO
        // empty so its poll loads don't wait behind prefetches (vmcnt is FIFO)
        if (wid != 0 && t < NT - 1) {
            const float* p = x + ((size_t)(t + 1) * NB + b) * FS
                               + (size_t)bg * ELB + tid * 4;
            #pragma unroll
            for (int k = 0; k < CHK; ++k) xv[k] = *(const float4*)(p + k * (TPB * 4));
        }

        // ---- wave partial of sum |m_t| ----
        double ls = lsum;
        #pragma unroll
        for (int off = 32; off > 0; off >>= 1)
            ls += __shfl_down(ls, off, 64);
        if (lane == 0) dred[wid] = ls;
        __syncthreads();           // waves 1-3 then sleep at the next barrier

        if (tid < 64) {
            const double bs = (dred[0] + dred[1]) + (dred[2] + dred[3]);
            double* slot = bsum + (size_t)(t * NB + b) * BPB;
            if (!leader) {
                // follower: publish partial, 1-lane throttled poll of denom
                if (lane == 0) {
                    __hip_atomic_store(slot + bg, -bs, __ATOMIC_RELAXED,
                                       __HIP_MEMORY_SCOPE_AGENT);
                    double dv; long it = 0;
                    for (;;) {
                        dv = __hip_atomic_load(&dbc[t * NB + b], __ATOMIC_RELAXED,
                                               __HIP_MEMORY_SCOPE_AGENT);
                        if (__double_as_longlong(dv) != 0) break;
                        if (++it > SPIN_CAP) break;
                        __builtin_amdgcn_s_sleep(4);   // ~256 cyc backoff
                    }
                    denom_s = dv;
                }
            } else {
                // leader: gather 63 partials (own local at lane 0), bcast
                const bool act = (lane >= 1);
                double v = 0.0; long it = 0;
                for (;;) {
                    if (act)
                        v = __hip_atomic_load(slot + lane, __ATOMIC_RELAXED,
                                              __HIP_MEMORY_SCOPE_AGENT);
                    if (__all(!act || __double_as_longlong(v) != 0)) break;
                    if (++it > SPIN_CAP) break;
                    __builtin_amdgcn_s_sleep(1);       // ~64 cyc cadence
                }
                // slot i at lane i -> same 64-lane tree order as R1 (known-good)
                double tot = (lane == 0) ? bs : -v;
                #pragma unroll
                for (int off = 32; off > 0; off >>= 1)
                    tot += __shfl_down(tot, off, 64);
                if (lane == 0) {
                    const double dn = tot / (double)FS + 1e-6;  // exact /2^18
                    __hip_atomic_store(&dbc[t * NB + b], dn, __ATOMIC_RELAXED,
                                       __HIP_MEMORY_SCOPE_AGENT);
                    denom_s = dn;
                }
            }
            // deferred prefetch for the exchange wave (polls are done)
            if (t < NT - 1) {
                const float* p = x + ((size_t)(t + 1) * NB + b) * FS
                                   + (size_t)bg * ELB + tid * 4;
                #pragma unroll
                for (int k = 0; k < CHK; ++k)
                    xv[k] = *(const float4*)(p + k * (TPB * 4));
            }
        }
        __syncthreads();
        const double denom = denom_s;

        // fused threshold + advance:
        //   s_t  = (u >= vth*D_t)            (== m/D >= vth up to ~1e-15)
        //   u'   = (dec/D_t)*u + x' - s_t*(dec*vth)
        const double thr = vth * denom;
        const double a   = dec * (1.0 / denom);
        unsigned smt = 0;
        if (t < NT - 1) {
            double n0 = 0.0, n1 = 0.0, n2 = 0.0, n3 = 0.0;
            #pragma unroll
            for (int k = 0; k < CHK; ++k) {
                const double xn0 = (double)xv[k].x, xn1 = (double)xv[k].y,
                             xn2 = (double)xv[k].z, xn3 = (double)xv[k].w;
                double un;
                bool s0 = (u[k*4+0] >= thr); if (s0) smt |= 1u << (k*4+0);
                un = fma(a, u[k*4+0], xn0); if (s0) un -= csub;
                u[k*4+0] = un; n0 += fabs(un);
                bool s1 = (u[k*4+1] >= thr); if (s1) smt |= 1u << (k*4+1);
                un = fma(a, u[k*4+1], xn1); if (s1) un -= csub;
                u[k*4+1] = un; n1 += fabs(un);
                bool s2 = (u[k*4+2] >= thr); if (s2) smt |= 1u << (k*4+2);
                un = fma(a, u[k*4+2], xn2); if (s2) un -= csub;
                u[k*4+2] = un; n2 += fabs(un);
                bool s3 = (u[k*4+3] >= thr); if (s3) smt |= 1u << (k*4+3);
                un = fma(a, u[k*4+3], xn3); if (s3) un -= csub;
                u[k*4+3] = un; n3 += fabs(un);
            }
            lsum = (n0 + n1) + (n2 + n3);
        } else {
            #pragma unroll
            for (int j = 0; j < CHK * 4; ++j)
                if (u[j] >= thr) smt |= 1u << j;
        }
        sm[t] = smt;
    }

    // ---- spike counts per (t,b): exact ints, slots reused via sign flip ----
    __shared__ int ired[NT][4];
    #pragma unroll
    for (int t = 0; t < NT; ++t) {
        int c = __popc(sm[t]);
        #pragma unroll
        for (int off = 32; off > 0; off >>= 1)
            c += __shfl_down(c, off, 64);
        if (lane == 0) ired[t][wid] = c;
    }
    __syncthreads();

    __shared__ int totc_s[NT];
    __shared__ double summ_s[NT];

    if (tid < 64) {
        if (!leader) {
            // publish count_t+1 (positive; stale slot is -bs <= -0.0)
            if (lane < NT) {
                int tot = (ired[lane][0] + ired[lane][1])
                        + (ired[lane][2] + ired[lane][3]);
                __hip_atomic_store(&bsum[(size_t)(lane * NB + b) * BPB + bg],
                                   (double)(tot + 1), __ATOMIC_RELAXED,
                                   __HIP_MEMORY_SCOPE_AGENT);
            }
            // poll totals: ready when dbc goes negative
            const bool act = (lane < NT);
            double cv = 1.0; long it = 0;
            for (;;) {
                if (act)
                    cv = __hip_atomic_load(&dbc[lane * NB + b], __ATOMIC_RELAXED,
                                           __HIP_MEMORY_SCOPE_AGENT);
                if (__all(!act || cv < 0.0)) break;
                if (++it > SPIN_CAP) break;
                __builtin_amdgcn_s_sleep(4);
            }
            if (act) totc_s[lane] = (int)(-cv) - 1;
        } else {
            #pragma unroll 1
            for (int t = 0; t < NT; ++t) {
                const bool act = (lane >= 1);
                double v = 0.0; long it = 0;
                for (;;) {
                    if (act)
                        v = __hip_atomic_load(
                                &bsum[(size_t)(t * NB + b) * BPB + lane],
                                __ATOMIC_RELAXED, __HIP_MEMORY_SCOPE_AGENT);
                    if (__all(!act || v > 0.0)) break;
                    if (++it > SPIN_CAP) break;
                    __builtin_amdgcn_s_sleep(1);
                }
                int s = (lane == 0)
                          ? (ired[t][0] + ired[t][1]) + (ired[t][2] + ired[t][3])
                          : (int)v - 1;
                #pragma unroll
                for (int off = 32; off > 0; off >>= 1)
                    s += __shfl_down(s, off, 64);
                if (lane == 0) {
                    totc_s[t] = s;
                    __hip_atomic_store(&dbc[t * NB + b], -(double)(s + 1),
                                       __ATOMIC_RELAXED, __HIP_MEMORY_SCOPE_AGENT);
                }
            }
        }
    }
    __syncthreads();
    if (tid < NT)
        summ_s[tid] = (double)totc_s[tid] / (double)FS;    // exact
    __syncthreads();

    // ---- tiny MLP attention in fp64, redundantly per block ----
    __shared__ double h_s[4 * 64];
    __shared__ double wmat_s[NT];
    {
        int nh = tid >> 6, hd = tid & 63;
        double acc = 0.0;
        #pragma unroll
        for (int t = 0; t < NT; ++t)
            acc += summ_s[t] * (double)W1[nh * 512 + hd * 8 + t];
        acc += (double)b1[nh * 64 + hd];
        h_s[tid] = fmax(acc, 0.0);
    }
    __syncthreads();
    if (tid < NT) {
        double w = 0.0;
        for (int nh = 0; nh < 4; ++nh) {
            double macc = 0.0;
            for (int hd = 0; hd < 64; ++hd)
                macc += h_s[nh * 64 + hd] * (double)W2[nh * 512 + tid * 64 + hd];
            macc += (double)b2[nh * 8 + tid];
            w += macc * (double)att_w[nh];
        }
        wmat_s[tid] = w;
    }
    __syncthreads();

    // softmax over t in fp64 (per-thread copy)
    double awr[NT];
    {
        double mx = wmat_s[0];
        #pragma unroll
        for (int t = 1; t < NT; ++t) mx = fmax(mx, wmat_s[t]);
        double ss = 0.0;
        #pragma unroll
        for (int t = 0; t < NT; ++t) { awr[t] = exp(wmat_s[t] - mx); ss += awr[t]; }
        #pragma unroll
        for (int t = 0; t < NT; ++t) awr[t] = awr[t] / ss;
    }

    // ---- out[b,f] = sum_t spike_bit * aw[t,b] (fp64 acc, fp32 store) ----
    float* po = out + (size_t)b * FS + (size_t)bg * ELB + tid * 4;
    #pragma unroll
    for (int k = 0; k < CHK; ++k) {
        double o[4] = {0.0, 0.0, 0.0, 0.0};
        #pragma unroll
        for (int t = 0; t < NT; ++t) {
            const unsigned smt = sm[t];
            o[0] += ((smt >> (k * 4 + 0)) & 1) ? awr[t] : 0.0;
            o[1] += ((smt >> (k * 4 + 1)) & 1) ? awr[t] : 0.0;
            o[2] += ((smt >> (k * 4 + 2)) & 1) ? awr[t] : 0.0;
            o[3] += ((smt >> (k * 4 + 3)) & 1) ? awr[t] : 0.0;
        }
        *(float4*)(po + k * (TPB * 4)) =
            make_float4((float)o[0], (float)o[1], (float)o[2], (float)o[3]);
    }
}

__global__ void diag_kernel(float* out, int code) {
    out[0] = 100000.0f + (float)code;
}

extern "C" void kernel_launch(void* const* d_in, const int* in_sizes, int n_in,
                              void* d_out, int out_size, void* d_ws, size_t ws_size,
                              hipStream_t stream) {
    const float* x     = (const float*)d_in[0];
    const float* decay = (const float*)d_in[1];
    const float* vth   = (const float*)d_in[2];
    const float* W1    = (const float*)d_in[3];
    const float* b1    = (const float*)d_in[4];
    const float* W2    = (const float*)d_in[5];
    const float* b2    = (const float*)d_in[6];
    const float* att   = (const float*)d_in[7];
    float* out = (float*)d_out;

    if (ws_size < WS_NEED) {
        diag_kernel<<<1, 1, 0, stream>>>(out, 999);
        return;
    }

    double* bsum = (double*)d_ws;
    double* dbc  = (double*)((char*)d_ws + 65536);

    // flag region zeroed every launch (ws re-poisoned 0xAA between runs)
    hipMemsetAsync(d_ws, 0, WS_NEED, stream);

    hipGetLastError();  // clear stale error
    bispike_kernel<<<dim3(GRID), dim3(TPB), 0, stream>>>(
        x, decay, vth, W1, b1, W2, b2, att, out, bsum, dbc);
    hipError_t err = hipGetLastError();
    if (err != hipSuccess) {
        diag_kernel<<<1, 1, 0, stream>>>(out, (int)err);
    }
}